// Round 1
// baseline (675.895 us; speedup 1.0000x reference)
//
#include <hip/hip_runtime.h>

// Maxish: x [B,T,X,N=256] f32, scale scalar f32 -> out [B,T,X] f32.
// rho_max = max_n x
// rt      = (x - rho_max) / (rho_max + 1e-8)
// pos     = rho_max * sum(exp(s*rt)*exp(rt)) / sum(exp(s*rt))   [softmax shift = 0, exact for s>=0 since max(rt)=0]
// neg     = rho_max                                              [softmax sums to 1]
// out     = rm>0 ? pos : (rm<0 ? neg : 0)

#define SMALL_NUMBER 1e-8f
#define NCOL 256  // last-dim size, fixed by problem shape

__global__ __launch_bounds__(256, 8) void maxish_kernel(
    const float* __restrict__ x,
    const float* __restrict__ scale_p,
    float* __restrict__ out,
    int rows)
{
    const float s = scale_p[0];           // wave-uniform scalar
    const int lane  = threadIdx.x & 63;
    const int sub   = lane & 15;          // lane within 16-lane row-group
    const int grp   = lane >> 4;          // which of the 4 rows this wave handles
    const int wib   = threadIdx.x >> 6;
    const int wpb   = blockDim.x >> 6;
    const int gwave = blockIdx.x * wpb + wib;
    const int nwav  = gridDim.x * wpb;

    // each wave-iteration processes 4 consecutive rows (4 KiB contiguous)
    for (int r4 = gwave; r4 * 4 < rows; r4 += nwav) {
        const int row = r4 * 4 + grp;
        if (row >= rows) break;
        const float4* p = reinterpret_cast<const float4*>(x + (size_t)row * NCOL);

        // lane covers cols {k*64 + sub*4 .. +3}, k=0..3 -> each load instr is
        // 4x256B contiguous segments across the wave (fully coalesced)
        float4 v0 = p[ 0 + sub];
        float4 v1 = p[16 + sub];
        float4 v2 = p[32 + sub];
        float4 v3 = p[48 + sub];

        // ---- row max (16-lane butterfly) ----
        float mx = fmaxf(fmaxf(fmaxf(v0.x, v0.y), fmaxf(v0.z, v0.w)),
                   fmaxf(fmaxf(fmaxf(v1.x, v1.y), fmaxf(v1.z, v1.w)),
                   fmaxf(fmaxf(fmaxf(v2.x, v2.y), fmaxf(v2.z, v2.w)),
                         fmaxf(fmaxf(v3.x, v3.y), fmaxf(v3.z, v3.w)))));
        #pragma unroll
        for (int off = 8; off >= 1; off >>= 1)
            mx = fmaxf(mx, __shfl_xor(mx, off, 16));

        const float inv = 1.0f / (mx + SMALL_NUMBER);

        // ---- fused pos-branch sums ----
        float num = 0.0f, den = 0.0f;
        auto proc = [&](float xv) {
            float rt = (xv - mx) * inv;      // <= 0 when mx > 0; max is exactly 0
            float ed = __expf(s * rt);       // softmax numerator (shift 0)
            float en = ed * __expf(rt);      // weighted term
            den += ed;
            num += en;
        };
        proc(v0.x); proc(v0.y); proc(v0.z); proc(v0.w);
        proc(v1.x); proc(v1.y); proc(v1.z); proc(v1.w);
        proc(v2.x); proc(v2.y); proc(v2.z); proc(v2.w);
        proc(v3.x); proc(v3.y); proc(v3.z); proc(v3.w);

        #pragma unroll
        for (int off = 8; off >= 1; off >>= 1) {
            num += __shfl_xor(num, off, 16);
            den += __shfl_xor(den, off, 16);
        }

        // ---- select branch (bitwise select: no NaN contamination) ----
        float res;
        if (mx > 0.0f)      res = mx * (num / den);
        else if (mx < 0.0f) res = mx;   // neg branch: softmax sums to 1 -> rho_max
        else                res = 0.0f;

        if (sub == 0) out[row] = res;   // 4 consecutive floats per wave
    }
}

extern "C" void kernel_launch(void* const* d_in, const int* in_sizes, int n_in,
                              void* d_out, int out_size, void* d_ws, size_t ws_size,
                              hipStream_t stream) {
    const float* x     = (const float*)d_in[0];
    const float* scale = (const float*)d_in[1];
    float* out         = (float*)d_out;

    const int rows = in_sizes[0] / NCOL;   // B*T*X = 524288

    const int block = 256;                 // 4 waves/block
    int grid = 2048;                       // 8 blocks/CU -> 32 waves/CU, grid-stride
    int need = (rows + 15) / 16;           // 4 rows per wave-iter, 4 waves/block
    if (grid > need) grid = need;

    maxish_kernel<<<grid, block, 0, stream>>>(x, scale, out, rows);
}